// Round 1
// baseline (5644.529 us; speedup 1.0000x reference)
//
#include <hip/hip_runtime.h>

// ---------------------------------------------------------------------------
// GCN forward: 4 x (H = X@W ; AGG = scatter(norm * H[src] -> dst) + self ; +b ; relu)
// then global mean pool over sorted batch ids, then 128->10 linear head.
// Output: y[512*10] ++ global_mean[512*128], fp32.
// ---------------------------------------------------------------------------

#define ATOMIC_ADD_F32(p, v) __hip_atomic_fetch_add((p), (v), __ATOMIC_RELAXED, __HIP_MEMORY_SCOPE_AGENT)

constexpr int NG = 512;   // NUM_GRAPHS
constexpr int HID = 128;

// --- degree ---------------------------------------------------------------
__global__ __launch_bounds__(256) void k_deg_init(int* __restrict__ deg, int N) {
    int i = blockIdx.x * 256 + threadIdx.x;
    if (i < N) deg[i] = 1;   // self-loop
}

__global__ __launch_bounds__(256) void k_deg_count(const int* __restrict__ dst,
                                                   int* __restrict__ deg, int E) {
    int i = blockIdx.x * 256 + threadIdx.x;
    int stride = gridDim.x * 256;
    for (; i < E; i += stride) atomicAdd(&deg[dst[i]], 1);
}

__global__ __launch_bounds__(256) void k_dinv(const int* __restrict__ deg,
                                              float* __restrict__ dinv, int N) {
    int i = blockIdx.x * 256 + threadIdx.x;
    if (i < N) dinv[i] = rsqrtf((float)deg[i]);
}

// --- GEMM: H = act(X) @ W ; AGG = H * dinv^2 (self-loop term) ---------------
// act(X) = use_bias ? relu(X + bias_prev) : X   (bias/relu of PREVIOUS layer fused here)
// block: 256 threads, 64 rows, 128 cols. W (64KB) + Xtile (32KB) in LDS.
__global__ __launch_bounds__(256) void k_gemm(const float* __restrict__ X,
                                              const float* __restrict__ W,
                                              const float* __restrict__ bias_prev,
                                              const float* __restrict__ dinv,
                                              float* __restrict__ H,
                                              float* __restrict__ AGG,
                                              int N, int use_bias) {
    __shared__ float Ws[128 * 128];
    __shared__ float Xs[64 * 128];
    const int tid = threadIdx.x;

    // stage W: 16384 floats = 4096 float4 / 256 threads = 16 each
    const float4* W4 = (const float4*)W;
    float4* Ws4 = (float4*)Ws;
#pragma unroll
    for (int i = 0; i < 16; ++i) Ws4[i * 256 + tid] = W4[i * 256 + tid];

    const int row0 = blockIdx.x * 64;
    const int nrows = min(64, N - row0);

    // stage X rows (with fused bias+relu of previous layer)
    const float4* X4 = (const float4*)(X + (size_t)row0 * 128);
    float4* Xs4 = (float4*)Xs;
    for (int i = tid; i < nrows * 32; i += 256) {
        float4 v = X4[i];
        if (use_bias) {
            int k = (i & 31) * 4;
            v.x = fmaxf(v.x + bias_prev[k + 0], 0.f);
            v.y = fmaxf(v.y + bias_prev[k + 1], 0.f);
            v.z = fmaxf(v.z + bias_prev[k + 2], 0.f);
            v.w = fmaxf(v.w + bias_prev[k + 3], 0.f);
        }
        Xs4[i] = v;
    }
    __syncthreads();

    const int c0 = (tid & 31) * 4;       // 4 consecutive output cols
    const int rg = (tid >> 5) * 8;       // 8 rows per thread
    float4 acc[8];
#pragma unroll
    for (int r = 0; r < 8; ++r) acc[r] = make_float4(0.f, 0.f, 0.f, 0.f);

    for (int k = 0; k < 128; ++k) {
        float4 w = *(const float4*)&Ws[k * 128 + c0];
#pragma unroll
        for (int r = 0; r < 8; ++r) {
            float xv = Xs[(rg + r) * 128 + k];
            acc[r].x = fmaf(xv, w.x, acc[r].x);
            acc[r].y = fmaf(xv, w.y, acc[r].y);
            acc[r].z = fmaf(xv, w.z, acc[r].z);
            acc[r].w = fmaf(xv, w.w, acc[r].w);
        }
    }

#pragma unroll
    for (int r = 0; r < 8; ++r) {
        int lr = rg + r;
        if (lr < nrows) {
            size_t off = (size_t)(row0 + lr) * 128 + c0;
            *(float4*)&H[off] = acc[r];
            float di = dinv[row0 + lr];
            float s = di * di;
            float4 a = make_float4(acc[r].x * s, acc[r].y * s, acc[r].z * s, acc[r].w * s);
            *(float4*)&AGG[off] = a;
        }
    }
}

// --- edge scatter: AGG[dst] += dinv[src]*dinv[dst] * H[src] -----------------
// one wave per edge; lane handles float2 (128 floats / 64 lanes)
__global__ __launch_bounds__(256) void k_edge_scatter(const int* __restrict__ src,
                                                      const int* __restrict__ dst,
                                                      const float* __restrict__ dinv,
                                                      const float* __restrict__ H,
                                                      float* __restrict__ AGG, int E) {
    int e = blockIdx.x * 4 + (threadIdx.x >> 6);
    if (e >= E) return;
    int lane = threadIdx.x & 63;
    int s = src[e], d = dst[e];
    float nrm = dinv[s] * dinv[d];
    float2 v = ((const float2*)(H + (size_t)s * 128))[lane];
    float* arow = AGG + (size_t)d * 128 + lane * 2;
    ATOMIC_ADD_F32(arow + 0, v.x * nrm);
    ATOMIC_ADD_F32(arow + 1, v.y * nrm);
}

// --- pool: pooled[g] += relu(AGG[i] + b) for batch[i]==g (batch sorted) -----
// block = 128 threads (one per channel), 64 nodes per block, segmented reduce.
__global__ __launch_bounds__(128) void k_pool(const float* __restrict__ H,
                                              const float* __restrict__ b,
                                              const int* __restrict__ batch,
                                              float* __restrict__ pooled,
                                              float* __restrict__ counts, int N) {
    int k = threadIdx.x;
    int i0 = blockIdx.x * 64;
    if (i0 >= N) return;
    int iend = min(i0 + 64, N);
    float bk = b[k];
    float acc = 0.f;
    int cnt = 0;
    int cur = batch[i0];
    for (int i = i0; i < iend; ++i) {
        int g = batch[i];
        if (g != cur) {
            ATOMIC_ADD_F32(&pooled[cur * 128 + k], acc);
            if (k == 0) ATOMIC_ADD_F32(&counts[cur], (float)cnt);
            acc = 0.f; cnt = 0; cur = g;
        }
        acc += fmaxf(H[(size_t)i * 128 + k] + bk, 0.f);
        cnt++;
    }
    ATOMIC_ADD_F32(&pooled[cur * 128 + k], acc);
    if (k == 0) ATOMIC_ADD_F32(&counts[cur], (float)cnt);
}

// --- finalize: global_mean + head -------------------------------------------
__global__ __launch_bounds__(128) void k_finalize(const float* __restrict__ pooled,
                                                  const float* __restrict__ counts,
                                                  const float* __restrict__ Wl,
                                                  const float* __restrict__ bl,
                                                  float* __restrict__ out) {
    int g = blockIdx.x;
    int t = threadIdx.x;
    __shared__ float m[128];
    float c = fmaxf(counts[g], 1.f);
    float mean = pooled[g * 128 + t] / c;
    out[NG * 10 + g * 128 + t] = mean;   // global_mean part
    m[t] = mean;
    __syncthreads();
    if (t < 10) {
        float acc = bl[t];
#pragma unroll 16
        for (int k = 0; k < 128; ++k) acc = fmaf(m[k], Wl[k * 10 + t], acc);
        out[g * 10 + t] = acc;           // y part
    }
}

// ---------------------------------------------------------------------------
extern "C" void kernel_launch(void* const* d_in, const int* in_sizes, int n_in,
                              void* d_out, int out_size, void* d_ws, size_t ws_size,
                              hipStream_t stream) {
    const float* x     = (const float*)d_in[0];
    const int*   ei    = (const int*)d_in[1];
    const int*   batch = (const int*)d_in[2];
    const float* Wt[4] = { (const float*)d_in[3], (const float*)d_in[5],
                           (const float*)d_in[7], (const float*)d_in[9] };
    const float* bt[4] = { (const float*)d_in[4], (const float*)d_in[6],
                           (const float*)d_in[8], (const float*)d_in[10] };
    const float* Wl = (const float*)d_in[11];
    const float* bl = (const float*)d_in[12];
    float* out = (float*)d_out;

    const int N = in_sizes[0] / 128;
    const int E = in_sizes[1] / 2;
    const int* src = ei;
    const int* dst = ei + E;

    // workspace layout
    char* p = (char*)d_ws;
    float* H    = (float*)p;                 p += (size_t)N * 128 * 4;
    float* AGG  = (float*)p;                 p += (size_t)N * 128 * 4;
    float* dinv = (float*)p;                 p += (size_t)N * 4;
    int*   deg  = (int*)p;                   p += (size_t)N * 4;
    float* pooled = (float*)p;               p += (size_t)NG * 128 * 4;
    float* counts = (float*)p;               p += (size_t)NG * 4;

    // degrees
    k_deg_init<<<(N + 255) / 256, 256, 0, stream>>>(deg, N);
    k_deg_count<<<1024, 256, 0, stream>>>(dst, deg, E);
    k_dinv<<<(N + 255) / 256, 256, 0, stream>>>(deg, dinv, N);

    // layers
    const int gemm_blocks = (N + 63) / 64;
    const int edge_blocks = (E + 3) / 4;
    const float* in = x;
    const float* bprev = nullptr;
    int use_bias = 0;
    for (int l = 0; l < 4; ++l) {
        k_gemm<<<gemm_blocks, 256, 0, stream>>>(in, Wt[l], bprev, dinv, H, AGG, N, use_bias);
        k_edge_scatter<<<edge_blocks, 256, 0, stream>>>(src, dst, dinv, H, AGG, E);
        in = AGG;
        bprev = bt[l];
        use_bias = 1;
    }

    // pool + head
    hipMemsetAsync(pooled, 0, (size_t)(NG * 128 + NG) * 4, stream);
    k_pool<<<(N + 63) / 64, 128, 0, stream>>>(AGG, bt[3], batch, pooled, counts, N);
    k_finalize<<<NG, 128, 0, stream>>>(pooled, counts, Wl, bl, out);
}

// Round 2
// 1035.719 us; speedup vs baseline: 5.4499x; 5.4499x over previous
//
#include <hip/hip_runtime.h>

// ---------------------------------------------------------------------------
// GCN forward, CSR-gather aggregation (no fp32 atomics on feature rows).
// 4 x (H = act(X)@W ; AGG[d] = dinv[d]*(sum_{s in N(d)} dinv[s]*H[s] + dinv[d]*H[d]))
// then global mean pool over sorted batch ids, then 128->10 linear head.
// Output: y[512*10] ++ global_mean[512*128], fp32.
// ---------------------------------------------------------------------------

#define ATOMIC_ADD_F32(p, v) __hip_atomic_fetch_add((p), (v), __ATOMIC_RELAXED, __HIP_MEMORY_SCOPE_AGENT)

constexpr int NG = 512;   // NUM_GRAPHS

// --- degree ---------------------------------------------------------------
__global__ __launch_bounds__(256) void k_deg_init(int* __restrict__ deg, int N) {
    int i = blockIdx.x * 256 + threadIdx.x;
    if (i < N) deg[i] = 1;   // self-loop
}

__global__ __launch_bounds__(256) void k_deg_count(const int* __restrict__ dst,
                                                   int* __restrict__ deg, int E) {
    int i = blockIdx.x * 256 + threadIdx.x;
    int stride = gridDim.x * 256;
    for (; i < E; i += stride) atomicAdd(&deg[dst[i]], 1);
}

__global__ __launch_bounds__(256) void k_dinv(const int* __restrict__ deg,
                                              float* __restrict__ dinv, int N) {
    int i = blockIdx.x * 256 + threadIdx.x;
    if (i < N) dinv[i] = rsqrtf((float)deg[i]);
}

// --- exclusive scan of (deg[i]-1) -> rowptr[N+1] ----------------------------
__global__ __launch_bounds__(256) void k_scan_local(const int* __restrict__ deg,
                                                    int* __restrict__ rowptr,
                                                    int* __restrict__ partials, int N) {
    __shared__ int s[256];
    int t = threadIdx.x;
    int i = blockIdx.x * 256 + t;
    int v = (i < N) ? (deg[i] - 1) : 0;
    s[t] = v;
    __syncthreads();
    // Hillis-Steele inclusive scan
#pragma unroll
    for (int off = 1; off < 256; off <<= 1) {
        int add = (t >= off) ? s[t - off] : 0;
        __syncthreads();
        s[t] += add;
        __syncthreads();
    }
    if (i < N) rowptr[i] = s[t] - v;        // exclusive within block
    if (t == 255) partials[blockIdx.x] = s[t];
}

__global__ __launch_bounds__(512) void k_scan_partials(int* __restrict__ partials, int nblk) {
    __shared__ int s[512];
    int t = threadIdx.x;
    int v = (t < nblk) ? partials[t] : 0;
    s[t] = v;
    __syncthreads();
#pragma unroll
    for (int off = 1; off < 512; off <<= 1) {
        int add = (t >= off) ? s[t - off] : 0;
        __syncthreads();
        s[t] += add;
        __syncthreads();
    }
    if (t < nblk) partials[t] = s[t] - v;   // exclusive
}

__global__ __launch_bounds__(256) void k_scan_apply(const int* __restrict__ deg,
                                                    int* __restrict__ rowptr,
                                                    const int* __restrict__ partials, int N) {
    int i = blockIdx.x * 256 + threadIdx.x;
    if (i < N) {
        int r = rowptr[i] + partials[blockIdx.x];
        rowptr[i] = r;
        if (i == N - 1) rowptr[N] = r + deg[i] - 1;
    }
}

// --- CSR fill: bucket edges by dst ------------------------------------------
__global__ __launch_bounds__(256) void k_csr_fill(const int* __restrict__ src,
                                                  const int* __restrict__ dst,
                                                  const int* __restrict__ rowptr,
                                                  int* __restrict__ cursor,
                                                  int* __restrict__ csr_src, int E) {
    int i = blockIdx.x * 256 + threadIdx.x;
    int stride = gridDim.x * 256;
    for (; i < E; i += stride) {
        int d = dst[i];
        int pos = atomicAdd(&cursor[d], 1);
        csr_src[rowptr[d] + pos] = src[i];
    }
}

// --- GEMM: H = act(X) @ W ----------------------------------------------------
// act(X) = use_bias ? relu(X + bias_prev) : X   (bias/relu of PREVIOUS layer fused)
// block: 256 threads, 64 rows, 128 cols. W (64KB) + Xtile (32KB) in LDS.
__global__ __launch_bounds__(256) void k_gemm(const float* __restrict__ X,
                                              const float* __restrict__ W,
                                              const float* __restrict__ bias_prev,
                                              float* __restrict__ H,
                                              int N, int use_bias) {
    __shared__ float Ws[128 * 128];
    __shared__ float Xs[64 * 128];
    const int tid = threadIdx.x;

    const float4* W4 = (const float4*)W;
    float4* Ws4 = (float4*)Ws;
#pragma unroll
    for (int i = 0; i < 16; ++i) Ws4[i * 256 + tid] = W4[i * 256 + tid];

    const int row0 = blockIdx.x * 64;
    const int nrows = min(64, N - row0);

    const float4* X4 = (const float4*)(X + (size_t)row0 * 128);
    float4* Xs4 = (float4*)Xs;
    for (int i = tid; i < nrows * 32; i += 256) {
        float4 v = X4[i];
        if (use_bias) {
            int k = (i & 31) * 4;
            v.x = fmaxf(v.x + bias_prev[k + 0], 0.f);
            v.y = fmaxf(v.y + bias_prev[k + 1], 0.f);
            v.z = fmaxf(v.z + bias_prev[k + 2], 0.f);
            v.w = fmaxf(v.w + bias_prev[k + 3], 0.f);
        }
        Xs4[i] = v;
    }
    __syncthreads();

    const int c0 = (tid & 31) * 4;
    const int rg = (tid >> 5) * 8;
    float4 acc[8];
#pragma unroll
    for (int r = 0; r < 8; ++r) acc[r] = make_float4(0.f, 0.f, 0.f, 0.f);

    for (int k = 0; k < 128; ++k) {
        float4 w = *(const float4*)&Ws[k * 128 + c0];
#pragma unroll
        for (int r = 0; r < 8; ++r) {
            float xv = Xs[(rg + r) * 128 + k];
            acc[r].x = fmaf(xv, w.x, acc[r].x);
            acc[r].y = fmaf(xv, w.y, acc[r].y);
            acc[r].z = fmaf(xv, w.z, acc[r].z);
            acc[r].w = fmaf(xv, w.w, acc[r].w);
        }
    }

#pragma unroll
    for (int r = 0; r < 8; ++r) {
        int lr = rg + r;
        if (lr < nrows) {
            *(float4*)&H[(size_t)(row0 + lr) * 128 + c0] = acc[r];
        }
    }
}

// --- aggregate (CSR gather): one wave per dst node ---------------------------
__global__ __launch_bounds__(256) void k_aggregate(const int* __restrict__ csr_src,
                                                   const int* __restrict__ rowptr,
                                                   const float* __restrict__ dinv,
                                                   const float* __restrict__ H,
                                                   float* __restrict__ AGG, int N) {
    int d = blockIdx.x * 4 + (threadIdx.x >> 6);
    if (d >= N) return;
    int lane = threadIdx.x & 63;
    int beg = rowptr[d];
    int end = rowptr[d + 1];
    float dd = dinv[d];

    float2 self = ((const float2*)(H + (size_t)d * 128))[lane];
    float2 acc = make_float2(self.x * dd, self.y * dd);

    int j = beg;
    for (; j + 3 < end; j += 4) {
        int s0 = csr_src[j], s1 = csr_src[j + 1], s2 = csr_src[j + 2], s3 = csr_src[j + 3];
        float w0 = dinv[s0], w1 = dinv[s1], w2 = dinv[s2], w3 = dinv[s3];
        float2 v0 = ((const float2*)(H + (size_t)s0 * 128))[lane];
        float2 v1 = ((const float2*)(H + (size_t)s1 * 128))[lane];
        float2 v2 = ((const float2*)(H + (size_t)s2 * 128))[lane];
        float2 v3 = ((const float2*)(H + (size_t)s3 * 128))[lane];
        acc.x = fmaf(w0, v0.x, acc.x); acc.y = fmaf(w0, v0.y, acc.y);
        acc.x = fmaf(w1, v1.x, acc.x); acc.y = fmaf(w1, v1.y, acc.y);
        acc.x = fmaf(w2, v2.x, acc.x); acc.y = fmaf(w2, v2.y, acc.y);
        acc.x = fmaf(w3, v3.x, acc.x); acc.y = fmaf(w3, v3.y, acc.y);
    }
    for (; j < end; ++j) {
        int s = csr_src[j];
        float w = dinv[s];
        float2 v = ((const float2*)(H + (size_t)s * 128))[lane];
        acc.x = fmaf(w, v.x, acc.x);
        acc.y = fmaf(w, v.y, acc.y);
    }
    acc.x *= dd;
    acc.y *= dd;
    ((float2*)(AGG + (size_t)d * 128))[lane] = acc;
}

// --- pool: pooled[g] += relu(AGG[i] + b) for batch[i]==g (batch sorted) -----
__global__ __launch_bounds__(128) void k_pool(const float* __restrict__ H,
                                              const float* __restrict__ b,
                                              const int* __restrict__ batch,
                                              float* __restrict__ pooled,
                                              float* __restrict__ counts, int N) {
    int k = threadIdx.x;
    int i0 = blockIdx.x * 64;
    if (i0 >= N) return;
    int iend = min(i0 + 64, N);
    float bk = b[k];
    float acc = 0.f;
    int cnt = 0;
    int cur = batch[i0];
    for (int i = i0; i < iend; ++i) {
        int g = batch[i];
        if (g != cur) {
            ATOMIC_ADD_F32(&pooled[cur * 128 + k], acc);
            if (k == 0) ATOMIC_ADD_F32(&counts[cur], (float)cnt);
            acc = 0.f; cnt = 0; cur = g;
        }
        acc += fmaxf(H[(size_t)i * 128 + k] + bk, 0.f);
        cnt++;
    }
    ATOMIC_ADD_F32(&pooled[cur * 128 + k], acc);
    if (k == 0) ATOMIC_ADD_F32(&counts[cur], (float)cnt);
}

// --- finalize: global_mean + head -------------------------------------------
__global__ __launch_bounds__(128) void k_finalize(const float* __restrict__ pooled,
                                                  const float* __restrict__ counts,
                                                  const float* __restrict__ Wl,
                                                  const float* __restrict__ bl,
                                                  float* __restrict__ out) {
    int g = blockIdx.x;
    int t = threadIdx.x;
    __shared__ float m[128];
    float c = fmaxf(counts[g], 1.f);
    float mean = pooled[g * 128 + t] / c;
    out[NG * 10 + g * 128 + t] = mean;
    m[t] = mean;
    __syncthreads();
    if (t < 10) {
        float acc = bl[t];
#pragma unroll 16
        for (int k = 0; k < 128; ++k) acc = fmaf(m[k], Wl[k * 10 + t], acc);
        out[g * 10 + t] = acc;
    }
}

// ---------------------------------------------------------------------------
extern "C" void kernel_launch(void* const* d_in, const int* in_sizes, int n_in,
                              void* d_out, int out_size, void* d_ws, size_t ws_size,
                              hipStream_t stream) {
    const float* x     = (const float*)d_in[0];
    const int*   ei    = (const int*)d_in[1];
    const int*   batch = (const int*)d_in[2];
    const float* Wt[4] = { (const float*)d_in[3], (const float*)d_in[5],
                           (const float*)d_in[7], (const float*)d_in[9] };
    const float* bt[4] = { (const float*)d_in[4], (const float*)d_in[6],
                           (const float*)d_in[8], (const float*)d_in[10] };
    const float* Wl = (const float*)d_in[11];
    const float* bl = (const float*)d_in[12];
    float* out = (float*)d_out;

    const int N = in_sizes[0] / 128;
    const int E = in_sizes[1] / 2;
    const int* src = ei;
    const int* dst = ei + E;

    // workspace layout
    char* p = (char*)d_ws;
    float* H       = (float*)p;  p += (size_t)N * 128 * 4;
    float* AGG     = (float*)p;  p += (size_t)N * 128 * 4;
    float* dinv    = (float*)p;  p += (size_t)N * 4;
    int*   deg     = (int*)p;    p += (size_t)N * 4;
    int*   rowptr  = (int*)p;    p += (size_t)(N + 1) * 4;
    int*   cursor  = (int*)p;    p += (size_t)N * 4;
    int*   csr_src = (int*)p;    p += (size_t)E * 4;
    int*   partials= (int*)p;    p += 512 * 4;
    float* pooled  = (float*)p;  p += (size_t)NG * 128 * 4;
    float* counts  = (float*)p;  p += (size_t)NG * 4;

    const int nblk = (N + 255) / 256;

    // degrees + norms
    k_deg_init<<<nblk, 256, 0, stream>>>(deg, N);
    k_deg_count<<<1024, 256, 0, stream>>>(dst, deg, E);
    k_dinv<<<nblk, 256, 0, stream>>>(deg, dinv, N);

    // CSR build (by dst)
    k_scan_local<<<nblk, 256, 0, stream>>>(deg, rowptr, partials, N);
    k_scan_partials<<<1, 512, 0, stream>>>(partials, nblk);
    k_scan_apply<<<nblk, 256, 0, stream>>>(deg, rowptr, partials, N);
    hipMemsetAsync(cursor, 0, (size_t)N * 4, stream);
    k_csr_fill<<<1024, 256, 0, stream>>>(src, dst, rowptr, cursor, csr_src, E);

    // layers
    const int gemm_blocks = (N + 63) / 64;
    const int agg_blocks = (N + 3) / 4;
    const float* in = x;
    const float* bprev = nullptr;
    int use_bias = 0;
    for (int l = 0; l < 4; ++l) {
        k_gemm<<<gemm_blocks, 256, 0, stream>>>(in, Wt[l], bprev, H, N, use_bias);
        k_aggregate<<<agg_blocks, 256, 0, stream>>>(csr_src, rowptr, dinv, H, AGG, N);
        in = AGG;
        bprev = bt[l];
        use_bias = 1;
    }

    // pool + head
    hipMemsetAsync(pooled, 0, (size_t)(NG * 128 + NG) * 4, stream);
    k_pool<<<(N + 63) / 64, 128, 0, stream>>>(AGG, bt[3], batch, pooled, counts, N);
    k_finalize<<<NG, 128, 0, stream>>>(pooled, counts, Wl, bl, out);
}

// Round 3
// 869.892 us; speedup vs baseline: 6.4888x; 1.1906x over previous
//
#include <hip/hip_runtime.h>

// ---------------------------------------------------------------------------
// GCN forward, CSR-gather aggregation + bf16-split MFMA GEMM.
//   per layer: H = X @ W            (MFMA, x=hi+lo bf16 split, 3 products)
//              AGG[d] = act(dinv[d]^2*H[d] + sum_e w_e*H[src_e] + b)
// then global mean pool over sorted batch ids, then 128->10 linear head.
// Output: y[512*10] ++ global_mean[512*128], fp32.
// ---------------------------------------------------------------------------

#define ATOMIC_ADD_F32(p, v) __hip_atomic_fetch_add((p), (v), __ATOMIC_RELAXED, __HIP_MEMORY_SCOPE_AGENT)

constexpr int NG = 512;   // NUM_GRAPHS

typedef short short8 __attribute__((ext_vector_type(8)));
typedef float f32x4 __attribute__((ext_vector_type(4)));

__device__ __forceinline__ unsigned short f2bf(float x) {
    union { float f; unsigned u; } c; c.f = x;
    unsigned u = c.u + 0x7fffu + ((c.u >> 16) & 1u);   // RNE
    return (unsigned short)(u >> 16);
}
__device__ __forceinline__ float bf2f(unsigned short h) {
    union { unsigned u; float f; } c; c.u = ((unsigned)h) << 16;
    return c.f;
}

// --- degree ---------------------------------------------------------------
__global__ __launch_bounds__(256) void k_deg_init(int* __restrict__ deg, int N) {
    int i = blockIdx.x * 256 + threadIdx.x;
    if (i < N) deg[i] = 1;   // self-loop
}

__global__ __launch_bounds__(256) void k_deg_count(const int* __restrict__ dst,
                                                   int* __restrict__ deg, int E) {
    int i = blockIdx.x * 256 + threadIdx.x;
    int stride = gridDim.x * 256;
    for (; i < E; i += stride) atomicAdd(&deg[dst[i]], 1);
}

__global__ __launch_bounds__(256) void k_dinv(const int* __restrict__ deg,
                                              float* __restrict__ dinv, int N) {
    int i = blockIdx.x * 256 + threadIdx.x;
    if (i < N) dinv[i] = rsqrtf((float)deg[i]);
}

// --- exclusive scan of (deg[i]-1) -> rowptr[N+1] ----------------------------
__global__ __launch_bounds__(256) void k_scan_local(const int* __restrict__ deg,
                                                    int* __restrict__ rowptr,
                                                    int* __restrict__ partials, int N) {
    __shared__ int s[256];
    int t = threadIdx.x;
    int i = blockIdx.x * 256 + t;
    int v = (i < N) ? (deg[i] - 1) : 0;
    s[t] = v;
    __syncthreads();
#pragma unroll
    for (int off = 1; off < 256; off <<= 1) {
        int add = (t >= off) ? s[t - off] : 0;
        __syncthreads();
        s[t] += add;
        __syncthreads();
    }
    if (i < N) rowptr[i] = s[t] - v;
    if (t == 255) partials[blockIdx.x] = s[t];
}

__global__ __launch_bounds__(512) void k_scan_partials(int* __restrict__ partials, int nblk) {
    __shared__ int s[512];
    int t = threadIdx.x;
    int v = (t < nblk) ? partials[t] : 0;
    s[t] = v;
    __syncthreads();
#pragma unroll
    for (int off = 1; off < 512; off <<= 1) {
        int add = (t >= off) ? s[t - off] : 0;
        __syncthreads();
        s[t] += add;
        __syncthreads();
    }
    if (t < nblk) partials[t] = s[t] - v;
}

__global__ __launch_bounds__(256) void k_scan_apply(const int* __restrict__ deg,
                                                    int* __restrict__ rowptr,
                                                    const int* __restrict__ partials, int N) {
    int i = blockIdx.x * 256 + threadIdx.x;
    if (i < N) {
        int r = rowptr[i] + partials[blockIdx.x];
        rowptr[i] = r;
        if (i == N - 1) rowptr[N] = r + deg[i] - 1;
    }
}

// --- CSR fill: bucket edges by dst, with fused edge weights ------------------
// cursor pre-initialized to rowptr (d2d memcpy) -> atomicAdd yields abs position
__global__ __launch_bounds__(256) void k_csr_fill(const int* __restrict__ src,
                                                  const int* __restrict__ dst,
                                                  const float* __restrict__ dinv,
                                                  int* __restrict__ cursor,
                                                  int* __restrict__ csr_src,
                                                  float* __restrict__ csr_w, int E) {
    int i = blockIdx.x * 256 + threadIdx.x;
    int stride = gridDim.x * 256;
    for (; i < E; i += stride) {
        int d = dst[i];
        int s = src[i];
        int pos = atomicAdd(&cursor[d], 1);
        csr_src[pos] = s;
        csr_w[pos] = dinv[s] * dinv[d];
    }
}

// --- W prep: split fp32 W[k][c] into transposed bf16 hi/lo: Wt[c][k] ---------
__global__ __launch_bounds__(256) void k_wsplit(const float* __restrict__ W,
                                                unsigned short* __restrict__ Wth,
                                                unsigned short* __restrict__ Wtl) {
    int idx = blockIdx.x * 256 + threadIdx.x;   // 16384 total
    int k = idx >> 7, c = idx & 127;
    float w = W[idx];
    unsigned short hi = f2bf(w);
    float lo = w - bf2f(hi);
    Wth[c * 128 + k] = hi;
    Wtl[c * 128 + k] = f2bf(lo);
}

// --- GEMM: H = X @ W via bf16-split MFMA (3 products), no LDS ----------------
// block = 256 threads = 4 waves (2 row-halves x 2 col-halves). M=64/block.
// wave computes 32 rows x 64 cols = 2 rowtiles x 4 coltiles of 16x16x32 MFMA.
__global__ __launch_bounds__(256) void k_gemm_mfma(const float* __restrict__ X,
                                                   const unsigned short* __restrict__ Wth,
                                                   const unsigned short* __restrict__ Wtl,
                                                   float* __restrict__ H, int N) {
    const int tid = threadIdx.x;
    const int wave = tid >> 6;
    const int l = tid & 63;
    const int wrow = wave & 1;       // 0/1 -> rows 0-31 / 32-63 of block tile
    const int wcol = wave >> 1;      // 0/1 -> cols 0-63 / 64-127
    const int lr = l & 15;
    const int lkb = (l >> 4) * 8;

    const int row_base = blockIdx.x * 64 + wrow * 32;
    const int c_base = wcol * 64;

    f32x4 acc[2][4];
#pragma unroll
    for (int rt = 0; rt < 2; ++rt)
#pragma unroll
        for (int ct = 0; ct < 4; ++ct) acc[rt][ct] = (f32x4){0.f, 0.f, 0.f, 0.f};

#pragma unroll
    for (int ks = 0; ks < 4; ++ks) {
        const int koff = ks * 32 + lkb;

        // B fragments: Wt[c][k], 8 contiguous bf16 per lane
        short8 bh[4], bl[4];
#pragma unroll
        for (int ct = 0; ct < 4; ++ct) {
            size_t off = (size_t)(c_base + ct * 16 + lr) * 128 + koff;
            bh[ct] = *(const short8*)(Wth + off);
            bl[ct] = *(const short8*)(Wtl + off);
        }

        // A fragments: X row slices (fp32), split to hi/lo bf16 in-reg
        short8 ah[2], al[2];
#pragma unroll
        for (int rt = 0; rt < 2; ++rt) {
            int r = row_base + rt * 16 + lr;
            if (r >= N) r = N - 1;                 // clamp (stores guarded)
            const float* xp = X + (size_t)r * 128 + koff;
            float4 f0 = *(const float4*)xp;
            float4 f1 = *(const float4*)(xp + 4);
            float xs[8] = {f0.x, f0.y, f0.z, f0.w, f1.x, f1.y, f1.z, f1.w};
            short8 h, lo;
#pragma unroll
            for (int j = 0; j < 8; ++j) {
                unsigned short hb = f2bf(xs[j]);
                float rem = xs[j] - bf2f(hb);
                h[j] = (short)hb;
                lo[j] = (short)f2bf(rem);
            }
            ah[rt] = h;
            al[rt] = lo;
        }

        // 3-product accumulate (lo*lo dropped)
#pragma unroll
        for (int rt = 0; rt < 2; ++rt)
#pragma unroll
            for (int ct = 0; ct < 4; ++ct) {
                acc[rt][ct] = __builtin_amdgcn_mfma_f32_16x16x32_bf16(ah[rt], bh[ct], acc[rt][ct], 0, 0, 0);
                acc[rt][ct] = __builtin_amdgcn_mfma_f32_16x16x32_bf16(al[rt], bh[ct], acc[rt][ct], 0, 0, 0);
                acc[rt][ct] = __builtin_amdgcn_mfma_f32_16x16x32_bf16(ah[rt], bl[ct], acc[rt][ct], 0, 0, 0);
            }
    }

    // store: D frag: col = lane&15, row = (lane>>4)*4 + j
#pragma unroll
    for (int rt = 0; rt < 2; ++rt) {
        int r0 = row_base + rt * 16 + (l >> 4) * 4;
#pragma unroll
        for (int ct = 0; ct < 4; ++ct) {
            int col = c_base + ct * 16 + lr;
#pragma unroll
            for (int j = 0; j < 4; ++j) {
                int r = r0 + j;
                if (r < N) H[(size_t)r * 128 + col] = acc[rt][ct][j];
            }
        }
    }
}

// --- aggregate (CSR gather): one wave per dst node ---------------------------
// AGG[d] = act( dinv[d]^2*H[d] + sum_j csr_w[j]*H[csr_src[j]] + bias )
__global__ __launch_bounds__(256) void k_aggregate(const int* __restrict__ csr_src,
                                                   const float* __restrict__ csr_w,
                                                   const int* __restrict__ rowptr,
                                                   const float* __restrict__ dinv,
                                                   const float* __restrict__ H,
                                                   const float* __restrict__ bias,
                                                   float* __restrict__ AGG,
                                                   int N, int use_act) {
    int d = blockIdx.x * 4 + (threadIdx.x >> 6);
    if (d >= N) return;
    int lane = threadIdx.x & 63;
    int beg = rowptr[d];
    int end = rowptr[d + 1];
    float dd = dinv[d];
    float sw = dd * dd;

    float2 self = ((const float2*)(H + (size_t)d * 128))[lane];
    float ax = self.x * sw, ay = self.y * sw;

    int j = beg;
    for (; j + 7 < end; j += 8) {
        int s[8]; float w[8]; float2 v[8];
#pragma unroll
        for (int u = 0; u < 8; ++u) { s[u] = csr_src[j + u]; w[u] = csr_w[j + u]; }
#pragma unroll
        for (int u = 0; u < 8; ++u) v[u] = ((const float2*)(H + (size_t)s[u] * 128))[lane];
#pragma unroll
        for (int u = 0; u < 8; ++u) { ax = fmaf(w[u], v[u].x, ax); ay = fmaf(w[u], v[u].y, ay); }
    }
    for (; j < end; ++j) {
        int s = csr_src[j];
        float w = csr_w[j];
        float2 v = ((const float2*)(H + (size_t)s * 128))[lane];
        ax = fmaf(w, v.x, ax);
        ay = fmaf(w, v.y, ay);
    }

    if (use_act) {
        ax = fmaxf(ax + bias[2 * lane + 0], 0.f);
        ay = fmaxf(ay + bias[2 * lane + 1], 0.f);
    }
    ((float2*)(AGG + (size_t)d * 128))[lane] = make_float2(ax, ay);
}

// --- pool: pooled[g] += relu(AGG[i] + b) for batch[i]==g (batch sorted) -----
__global__ __launch_bounds__(128) void k_pool(const float* __restrict__ H,
                                              const float* __restrict__ b,
                                              const int* __restrict__ batch,
                                              float* __restrict__ pooled,
                                              float* __restrict__ counts, int N) {
    int k = threadIdx.x;
    int i0 = blockIdx.x * 64;
    if (i0 >= N) return;
    int iend = min(i0 + 64, N);
    float bk = b[k];
    float acc = 0.f;
    int cnt = 0;
    int cur = batch[i0];
    for (int i = i0; i < iend; ++i) {
        int g = batch[i];
        if (g != cur) {
            ATOMIC_ADD_F32(&pooled[cur * 128 + k], acc);
            if (k == 0) ATOMIC_ADD_F32(&counts[cur], (float)cnt);
            acc = 0.f; cnt = 0; cur = g;
        }
        acc += fmaxf(H[(size_t)i * 128 + k] + bk, 0.f);
        cnt++;
    }
    ATOMIC_ADD_F32(&pooled[cur * 128 + k], acc);
    if (k == 0) ATOMIC_ADD_F32(&counts[cur], (float)cnt);
}

// --- finalize: global_mean + head -------------------------------------------
__global__ __launch_bounds__(128) void k_finalize(const float* __restrict__ pooled,
                                                  const float* __restrict__ counts,
                                                  const float* __restrict__ Wl,
                                                  const float* __restrict__ bl,
                                                  float* __restrict__ out) {
    int g = blockIdx.x;
    int t = threadIdx.x;
    __shared__ float m[128];
    float c = fmaxf(counts[g], 1.f);
    float mean = pooled[g * 128 + t] / c;
    out[NG * 10 + g * 128 + t] = mean;
    m[t] = mean;
    __syncthreads();
    if (t < 10) {
        float acc = bl[t];
#pragma unroll 16
        for (int k = 0; k < 128; ++k) acc = fmaf(m[k], Wl[k * 10 + t], acc);
        out[g * 10 + t] = acc;
    }
}

// ---------------------------------------------------------------------------
extern "C" void kernel_launch(void* const* d_in, const int* in_sizes, int n_in,
                              void* d_out, int out_size, void* d_ws, size_t ws_size,
                              hipStream_t stream) {
    const float* x     = (const float*)d_in[0];
    const int*   ei    = (const int*)d_in[1];
    const int*   batch = (const int*)d_in[2];
    const float* Wt[4] = { (const float*)d_in[3], (const float*)d_in[5],
                           (const float*)d_in[7], (const float*)d_in[9] };
    const float* bt[4] = { (const float*)d_in[4], (const float*)d_in[6],
                           (const float*)d_in[8], (const float*)d_in[10] };
    const float* Wl = (const float*)d_in[11];
    const float* bl = (const float*)d_in[12];
    float* out = (float*)d_out;

    const int N = in_sizes[0] / 128;
    const int E = in_sizes[1] / 2;
    const int* src = ei;
    const int* dst = ei + E;

    // workspace layout
    char* p = (char*)d_ws;
    float* H       = (float*)p;  p += (size_t)N * 128 * 4;
    float* AGG     = (float*)p;  p += (size_t)N * 128 * 4;
    float* dinv    = (float*)p;  p += (size_t)N * 4;
    int*   deg     = (int*)p;    p += (size_t)N * 4;
    int*   rowptr  = (int*)p;    p += (size_t)(N + 1) * 4;
    int*   cursor  = (int*)p;    p += (size_t)N * 4;
    int*   csr_src = (int*)p;    p += (size_t)E * 4;
    float* csr_w   = (float*)p;  p += (size_t)E * 4;
    int*   partials= (int*)p;    p += 512 * 4;
    float* pooled  = (float*)p;  p += (size_t)NG * 128 * 4;
    float* counts  = (float*)p;  p += (size_t)NG * 4;
    unsigned short* Wsp = (unsigned short*)p; p += 4 * 2 * 128 * 128 * 2; // 4 layers x hi/lo

    const int nblk = (N + 255) / 256;

    // degrees + norms
    k_deg_init<<<nblk, 256, 0, stream>>>(deg, N);
    k_deg_count<<<1024, 256, 0, stream>>>(dst, deg, E);
    k_dinv<<<nblk, 256, 0, stream>>>(deg, dinv, N);

    // CSR build (by dst)
    k_scan_local<<<nblk, 256, 0, stream>>>(deg, rowptr, partials, N);
    k_scan_partials<<<1, 512, 0, stream>>>(partials, nblk);
    k_scan_apply<<<nblk, 256, 0, stream>>>(deg, rowptr, partials, N);
    hipMemcpyAsync(cursor, rowptr, (size_t)N * 4, hipMemcpyDeviceToDevice, stream);
    k_csr_fill<<<1024, 256, 0, stream>>>(src, dst, dinv, cursor, csr_src, csr_w, E);

    // W splits (hi/lo bf16, transposed)
    unsigned short* Wth[4]; unsigned short* Wtl[4];
    for (int l = 0; l < 4; ++l) {
        Wth[l] = Wsp + (size_t)l * 2 * 16384;
        Wtl[l] = Wth[l] + 16384;
        k_wsplit<<<64, 256, 0, stream>>>(Wt[l], Wth[l], Wtl[l]);
    }

    // layers
    const int gemm_blocks = (N + 63) / 64;
    const int agg_blocks = (N + 3) / 4;
    const float* in = x;
    for (int l = 0; l < 4; ++l) {
        k_gemm_mfma<<<gemm_blocks, 256, 0, stream>>>(in, Wth[l], Wtl[l], H, N);
        k_aggregate<<<agg_blocks, 256, 0, stream>>>(csr_src, csr_w, rowptr, dinv, H,
                                                    bt[l], AGG, N, (l < 3) ? 1 : 0);
        in = AGG;
    }

    // pool + head
    hipMemsetAsync(pooled, 0, (size_t)(NG * 128 + NG) * 4, stream);
    k_pool<<<(N + 63) / 64, 128, 0, stream>>>(AGG, bt[3], batch, pooled, counts, N);
    k_finalize<<<NG, 128, 0, stream>>>(pooled, counts, Wl, bl, out);
}